// Round 20
// baseline (133.742 us; speedup 1.0000x reference)
//
#include <hip/hip_runtime.h>

typedef __attribute__((ext_vector_type(8))) _Float16 f16x8;
typedef __attribute__((ext_vector_type(4))) _Float16 f16x4;
typedef __attribute__((ext_vector_type(4))) float f32x4;

#define D 128
#define NCH 256       // Pab channels: [0:128)=Pa'=Pa+b1, [128:256)=Pb
#define BNODES 16     // nodes per bucket-block
#define TILE 64       // edges per inner tile in main
#define SC_ILP 4      // edges per thread in scatter
#define PSTRIDE 136   // PaL row stride in ushorts (272B)

static __device__ __forceinline__ ushort f2h(float f) {
    _Float16 h = (_Float16)f;
    return __builtin_bit_cast(ushort, h);
}

// ---------- prep: convert weights + per-node histogram WITH rank capture ----------
__global__ void prep_kernel(const float* __restrict__ W1,
                            const float* __restrict__ W2,
                            const int* __restrict__ ecol,
                            ushort* __restrict__ w1abt,
                            ushort* __restrict__ w2t,
                            int* __restrict__ hist,
                            int* __restrict__ rank,
                            int E, int n_nodes)
{
    int gid = blockIdx.x * blockDim.x + threadIdx.x;
    if (gid < NCH * D) {
        int oc = gid >> 7, k = gid & 127;
        float v;
        if (oc < 128) v = W1[k * D + oc] - W1[(k + 128) * D + oc];
        else          v = W1[(k + 128) * D + (oc - 128)];
        w1abt[gid] = f2h(v);
    } else if (gid < NCH * D + D * D) {
        int id2 = gid - NCH * D;
        int oc = id2 >> 7, k = id2 & 127;
        w2t[id2] = f2h(W2[k * D + oc]);
    } else {
        int e = gid - (NCH * D + D * D);
        if (e < E) {
            int c = ecol[e];
            if ((unsigned)c >= (unsigned)n_nodes) c = 0;
            rank[e] = atomicAdd(&hist[c], 1);
        }
    }
}

// ---------- scan stage 1: per-block sums ----------
__global__ void scan1_kernel(const int* __restrict__ hist, int* __restrict__ partial, int N)
{
    __shared__ int s[256];
    int tid = threadIdx.x;
    int i = blockIdx.x * 256 + tid;
    s[tid] = (i < N) ? hist[i] : 0;
    __syncthreads();
    #pragma unroll
    for (int off = 128; off > 0; off >>= 1) {
        if (tid < off) s[tid] += s[tid + off];
        __syncthreads();
    }
    if (tid == 0) partial[blockIdx.x] = s[0];
}

// ---------- scan stage 2+3 fused ----------
__global__ void scan23_kernel(const int* __restrict__ hist, const int* __restrict__ partial,
                              int* __restrict__ ofs,
                              int nb, int N, int E)
{
    __shared__ int sp[256];
    __shared__ int s[256];
    int tid = threadIdx.x;

    int pv = (tid < nb) ? partial[tid] : 0;
    sp[tid] = pv;
    __syncthreads();
    #pragma unroll
    for (int off = 1; off < 256; off <<= 1) {
        int t = (tid >= off) ? sp[tid - off] : 0;
        __syncthreads();
        sp[tid] += t;
        __syncthreads();
    }
    const int bofs = (blockIdx.x > 0) ? sp[blockIdx.x - 1] : 0;

    int i = blockIdx.x * 256 + tid;
    int v = (i < N) ? hist[i] : 0;
    s[tid] = v;
    __syncthreads();
    #pragma unroll
    for (int off = 1; off < 256; off <<= 1) {
        int t = (tid >= off) ? s[tid - off] : 0;
        __syncthreads();
        s[tid] += t;
        __syncthreads();
    }
    if (i < N) ofs[i] = bofs + s[tid] - v;
    if (blockIdx.x == 0 && tid == 0) ofs[N] = E;
}

// ---------- fused: pab blocks [0,npab) + atomic-free scatter blocks [npab, ...) ----------
__global__ __launch_bounds__(256) void scatter_pab_kernel(
    const float* __restrict__ x,
    const ushort* __restrict__ w1abt,
    const float* __restrict__ b1,
    ushort* __restrict__ pab,
    const int* __restrict__ erow, const int* __restrict__ ecol,
    const int* __restrict__ nofs,
    const int* __restrict__ rank,
    unsigned* __restrict__ spk,
    int E, int n_nodes, int npab)
{
    __shared__ ushort A[64 * 128];   // used by pab blocks only
    const int tid = threadIdx.x;

    if ((int)blockIdx.x >= npab) {
        // ===== scatter: pure loads + one random store per edge, no atomics =====
        const int stride = (gridDim.x - npab) * 256;
        const int e0 = ((int)blockIdx.x - npab) * 256 + tid;
        int cc[SC_ILP], rr[SC_ILP], rk[SC_ILP];
        #pragma unroll
        for (int j = 0; j < SC_ILP; ++j) {
            int e = e0 + j * stride;
            if (e < E) {
                int c = ecol[e];
                if ((unsigned)c >= (unsigned)n_nodes) c = 0;
                int r = erow[e];
                if ((unsigned)r >= (unsigned)n_nodes) r = 0;
                cc[j] = c; rr[j] = r; rk[j] = rank[e];
            } else cc[j] = -1;
        }
        int pos[SC_ILP];
        #pragma unroll
        for (int j = 0; j < SC_ILP; ++j)
            if (cc[j] >= 0) pos[j] = nofs[cc[j]] + rk[j];
        #pragma unroll
        for (int j = 0; j < SC_ILP; ++j)
            if (cc[j] >= 0) spk[pos[j]] = (unsigned)cc[j] | ((unsigned)rr[j] << 16);
        return;
    }

    // ===== pab: Pab = x(fp16) @ [W1a | W1b] (+b1 folded into Pa') =====
    const int base = blockIdx.x * 64;

    #pragma unroll
    for (int it = 0; it < 8; ++it) {
        int idx4 = it * 256 + tid;       // float4 index in 64x128 tile
        int row = idx4 >> 5;
        int c4  = idx4 & 31;
        int node = base + row;
        float4 vx = make_float4(0.f, 0.f, 0.f, 0.f);
        if (node < n_nodes) vx = ((const float4*)x)[(size_t)node * 32 + c4];
        f16x4 o;
        o[0] = (_Float16)vx.x; o[1] = (_Float16)vx.y;
        o[2] = (_Float16)vx.z; o[3] = (_Float16)vx.w;
        *(f16x4*)((char*)A + row * 256 + ((c4 * 8) ^ ((row & 7) << 4))) = o;
    }
    __syncthreads();

    const int l = tid & 63, w = tid >> 6;
    const int l15 = l & 15, lq = l >> 4;

    f32x4 acc[4][4];                 // [channel frag][node frag]
    #pragma unroll
    for (int cf = 0; cf < 4; ++cf)
        #pragma unroll
        for (int rf = 0; rf < 4; ++rf)
            acc[cf][rf] = (f32x4){0.f, 0.f, 0.f, 0.f};

    #pragma unroll
    for (int kk = 0; kk < 4; ++kk) {
        f16x8 a[4], b[4];
        #pragma unroll
        for (int cf = 0; cf < 4; ++cf)
            a[cf] = *(const f16x8*)(w1abt + (w * 64 + cf * 16 + l15) * 128 + kk * 32 + lq * 8);
        #pragma unroll
        for (int rf = 0; rf < 4; ++rf) {
            int row = rf * 16 + l15;
            b[rf] = *(const f16x8*)((const char*)A + row * 256 + ((kk * 64 + lq * 16) ^ ((row & 7) << 4)));
        }
        #pragma unroll
        for (int cf = 0; cf < 4; ++cf)
            #pragma unroll
            for (int rf = 0; rf < 4; ++rf)
                acc[cf][rf] = __builtin_amdgcn_mfma_f32_16x16x32_f16(a[cf], b[rf], acc[cf][rf], 0, 0, 0);
    }

    // D[ch][node]: node = rf*16 + l15 (lane), ch = w*64 + cf*16 + lq*4 + r
    #pragma unroll
    for (int rf = 0; rf < 4; ++rf) {
        int node = base + rf * 16 + l15;
        if (node < n_nodes) {
            #pragma unroll
            for (int cf = 0; cf < 4; ++cf) {
                int ch = w * 64 + cf * 16 + lq * 4;
                float4 bb = (w < 2) ? *(const float4*)(b1 + ch) : make_float4(0.f, 0.f, 0.f, 0.f);
                f16x4 o;
                o[0] = (_Float16)(acc[cf][rf][0] + bb.x);
                o[1] = (_Float16)(acc[cf][rf][1] + bb.y);
                o[2] = (_Float16)(acc[cf][rf][2] + bb.z);
                o[3] = (_Float16)(acc[cf][rf][3] + bb.w);
                *(f16x4*)(pab + (size_t)node * NCH + ch) = o;
            }
        }
    }
}

// ================= main: PaL cache + double-buffered indices + vb payload pipeline =================
__global__ __launch_bounds__(256, 4) void edgeconv_main(
    const ushort* __restrict__ pab,
    const ushort* __restrict__ w2t,
    const unsigned* __restrict__ spk,
    const int* __restrict__ nofs,     // node-level offsets [n_nodes+1]
    const float* __restrict__ b2,
    float* __restrict__ out,
    int E, int n_nodes)
{
    __shared__ unsigned outbuf[BNODES * D];      // 8KB encoded running max
    __shared__ ushort Hs[TILE * D];              // 16KB h tile (fp16, swizzled)
    __shared__ ushort PaL[BNODES * PSTRIDE];     // 4.25KB bucket Pa' cache
    __shared__ int colb[2][TILE];
    __shared__ int rowb[2][TILE];

    const int tid = threadIdx.x;

    // XCD-bijective bucket swizzle
    const int nwg = gridDim.x, orig = blockIdx.x;
    const int q = nwg >> 3, rr = nwg & 7, xcd = orig & 7;
    const int bucket = (xcd < rr ? xcd * (q + 1) : rr * (q + 1) + (xcd - rr) * q) + (orig >> 3);

    const int base = bucket * BNODES;
    const int nend = min(base + BNODES, n_nodes);
    const int estart = nofs[base];
    const int eend = nofs[nend];

    #pragma unroll
    for (int i = 0; i < 8; ++i) outbuf[tid + i * 256] = 0u;

    const int l = tid & 63, w = tid >> 6;
    const int l15 = l & 15, lq = l >> 4;
    const int cg = tid & 15, esub = tid >> 4;
    const f16x8 zero = {0, 0, 0, 0, 0, 0, 0, 0};
    const unsigned padp = (unsigned)base | ((unsigned)base << 16);

    // load bucket's Pa' (16 nodes x 128 ch) into LDS once
    {
        int node = tid >> 4;
        int ch = (tid & 15) * 8;
        int gn = base + node;
        f16x8 v = zero;
        if (gn < n_nodes) v = *(const f16x8*)(pab + (size_t)gn * NCH + ch);
        *(f16x8*)(PaL + node * PSTRIDE + ch) = v;
    }

    // prologue: tile-0 indices -> colb/rowb[0]; px holds tile-1 indices
    unsigned px = padp;
    if (tid < TILE && estart + tid < eend) px = spk[estart + tid];
    if (tid < TILE) {
        colb[0][tid] = (int)(px & 0xffffu);
        rowb[0][tid] = (int)(px >> 16);
        int nt1 = estart + TILE + tid;
        px = (nt1 < eend) ? spk[nt1] : padp;
    }
    __syncthreads();   // PaL + tile-0 indices visible

    // issue vb(0) gathers
    f16x8 vb[4];
    if (estart < eend) {
        #pragma unroll
        for (int it = 0; it < 4; ++it) {
            int r = rowb[0][it * 16 + esub];
            vb[it] = *(const f16x8*)(pab + (size_t)r * NCH + 128 + cg * 8);
        }
    }

    int t = 0;
    for (int t0 = estart; t0 < eend; t0 += TILE, ++t) {
        const int cur = t & 1, nxt = cur ^ 1;
        const int n = min(TILE, eend - t0);
        const bool more = (t0 + TILE) < eend;

        // ---- h(t) = relu(PaL[col-base] + vb) -> Hs
        #pragma unroll
        for (int it = 0; it < 4; ++it) {
            int e = it * 16 + esub;
            int c = colb[cur][e] - base;
            f16x8 va = *(const f16x8*)(PaL + c * PSTRIDE + cg * 8);
            f16x8 h = __builtin_elementwise_max(va + vb[it], zero);
            *(f16x8*)((char*)Hs + e * 256 + ((cg * 16) ^ ((e & 7) << 4))) = h;
        }
        // stage t+1 indices into nxt buffer; fetch t+2's packed word
        if (tid < TILE) {
            colb[nxt][tid] = (int)(px & 0xffffu);
            rowb[nxt][tid] = (int)(px >> 16);
            int nn = t0 + 2 * TILE + tid;
            px = (nn < eend) ? spk[nn] : padp;
        }
        __syncthreads();   // Hs + nxt indices ready

        // ---- issue vb(t+1) gathers; complete under MFMA+epilogue
        if (more) {
            #pragma unroll
            for (int it = 0; it < 4; ++it) {
                int r = rowb[nxt][it * 16 + esub];
                vb[it] = *(const f16x8*)(pab + (size_t)r * NCH + 128 + cg * 8);
            }
        }

        // ---- layer 2: [64 x 128] @ [128 x 128]; wave w owns cols [w*32, w*32+32)
        f32x4 acc[4][2];
        #pragma unroll
        for (int mf = 0; mf < 4; ++mf)
            #pragma unroll
            for (int nf = 0; nf < 2; ++nf)
                acc[mf][nf] = (f32x4){0.f, 0.f, 0.f, 0.f};

        #pragma unroll
        for (int kk = 0; kk < 4; ++kk) {
            f16x8 a[4], b[2];
            #pragma unroll
            for (int mf = 0; mf < 4; ++mf) {
                int row = mf * 16 + l15;
                a[mf] = *(const f16x8*)((const char*)Hs + row * 256 + ((kk * 64 + lq * 16) ^ ((row & 7) << 4)));
            }
            #pragma unroll
            for (int nf = 0; nf < 2; ++nf) {
                int col = w * 32 + nf * 16 + l15;
                b[nf] = *(const f16x8*)(w2t + col * 128 + kk * 32 + lq * 8);
            }
            #pragma unroll
            for (int mf = 0; mf < 4; ++mf)
                #pragma unroll
                for (int nf = 0; nf < 2; ++nf)
                    acc[mf][nf] = __builtin_amdgcn_mfma_f32_16x16x32_f16(a[mf], b[nf], acc[mf][nf], 0, 0, 0);
        }

        // ---- epilogue: encoded LDS atomicMax (reads colb[cur])
        #pragma unroll
        for (int nf = 0; nf < 2; ++nf) {
            int col = w * 32 + nf * 16 + l15;
            #pragma unroll
            for (int mf = 0; mf < 4; ++mf) {
                #pragma unroll
                for (int r = 0; r < 4; ++r) {
                    int row = mf * 16 + lq * 4 + r;
                    if (row < n) {
                        int node = colb[cur][row] - base;
                        unsigned bs = __float_as_uint(acc[mf][nf][r]);
                        unsigned enc = (bs & 0x80000000u) ? ~bs : (bs | 0x80000000u);
                        atomicMax(&outbuf[node * D + col], enc);
                    }
                }
            }
        }
        __syncthreads();   // Hs free; colb[cur] free for overwrite in t+2
    }

    // ---- write 16 nodes x 128 ch, decode + b2, empty -> 0, coalesced float4
    const int n0 = tid >> 4;            // 0..15
    const int c0 = (tid & 15) * 8;      // 8 channels per thread
    const int gnode = base + n0;
    if (gnode < n_nodes) {
        #pragma unroll
        for (int j = 0; j < 2; ++j) {
            float4 o;
            #pragma unroll
            for (int k = 0; k < 4; ++k) {
                int ch = c0 + j * 4 + k;
                unsigned u = outbuf[n0 * D + ch];
                float v;
                if (u == 0u) v = 0.f;
                else {
                    unsigned bs = (u & 0x80000000u) ? (u & 0x7fffffffu) : ~u;
                    v = __uint_as_float(bs) + b2[ch];
                }
                ((float*)&o)[k] = v;
            }
            *(float4*)(out + (size_t)gnode * D + c0 + j * 4) = o;
        }
    }
}

extern "C" void kernel_launch(void* const* d_in, const int* in_sizes, int n_in,
                              void* d_out, int out_size, void* d_ws, size_t ws_size,
                              hipStream_t stream)
{
    const float* x  = (const float*)d_in[0];
    const int* eidx = (const int*)d_in[1];
    const float* W1 = (const float*)d_in[2];
    const float* b1 = (const float*)d_in[3];
    const float* W2 = (const float*)d_in[4];
    const float* b2 = (const float*)d_in[5];

    const int n_nodes = in_sizes[0] / D;      // 50000 (< 65536 -> packed pairs valid)
    const int E = in_sizes[1] / 2;
    const int* erow = eidx;        // edge_index[0]
    const int* ecol = eidx + E;    // edge_index[1]

    const int nb_scan = (n_nodes + 255) / 256;                  // 196 <= 256
    const int nbuckets = (n_nodes + BNODES - 1) / BNODES;       // 3125
    const int npab = (n_nodes + 63) / 64;                       // 782
    const int nsc = (E + 256 * SC_ILP - 1) / (256 * SC_ILP);    // 586

    // ---- workspace layout
    char* ws = (char*)d_ws;
    size_t off = 0;
    ushort* pab = (ushort*)(ws + off);   off += (size_t)n_nodes * NCH * sizeof(ushort);
    off = (off + 255) & ~(size_t)255;
    ushort* w1abt = (ushort*)(ws + off); off += (size_t)NCH * D * sizeof(ushort);
    ushort* w2t = (ushort*)(ws + off);   off += (size_t)D * D * sizeof(ushort);
    off = (off + 255) & ~(size_t)255;
    int* hist = (int*)(ws + off);        off += (size_t)n_nodes * 4;
    off = (off + 255) & ~(size_t)255;
    int* nofs = (int*)(ws + off);        off += (size_t)(n_nodes + 1) * 4;
    off = (off + 255) & ~(size_t)255;
    int* rank = (int*)(ws + off);        off += (size_t)E * 4;
    off = (off + 255) & ~(size_t)255;
    int* partial = (int*)(ws + off);     off += 256 * 4;
    off = (off + 255) & ~(size_t)255;
    unsigned* spk = (unsigned*)(ws + off); off += (size_t)E * 4;

    float* out = (float*)d_out;

    hipMemsetAsync(hist, 0, (size_t)n_nodes * sizeof(int), stream);

    const int prep_work = NCH * D + D * D + E;
    prep_kernel<<<(prep_work + 255) / 256, 256, 0, stream>>>(W1, W2, ecol, w1abt, w2t, hist, rank, E, n_nodes);

    scan1_kernel<<<nb_scan, 256, 0, stream>>>(hist, partial, n_nodes);
    scan23_kernel<<<nb_scan, 256, 0, stream>>>(hist, partial, nofs, nb_scan, n_nodes, E);

    scatter_pab_kernel<<<npab + nsc, 256, 0, stream>>>(x, w1abt, b1, pab, erow, ecol,
                                                       nofs, rank, spk, E, n_nodes, npab);

    edgeconv_main<<<nbuckets, 256, 0, stream>>>(pab, w2t, spk, nofs, b2, out, E, n_nodes);
}

// Round 21
// 130.269 us; speedup vs baseline: 1.0267x; 1.0267x over previous
//
#include <hip/hip_runtime.h>

typedef __attribute__((ext_vector_type(8))) _Float16 f16x8;
typedef __attribute__((ext_vector_type(4))) _Float16 f16x4;
typedef __attribute__((ext_vector_type(4))) float f32x4;

#define D 128
#define NCH 256       // Pab channels: [0:128)=Pa'=Pa+b1, [128:256)=Pb
#define BNODES 16     // nodes per bucket-block
#define TILE 64       // edges per inner tile in main
#define SC_ILP 4      // edges per thread in scatter
#define PSTRIDE 136   // PaL row stride in ushorts (272B)

static __device__ __forceinline__ ushort f2h(float f) {
    _Float16 h = (_Float16)f;
    return __builtin_bit_cast(ushort, h);
}

// ---------- prep: convert weights + per-node histogram WITH rank capture ----------
__global__ void prep_kernel(const float* __restrict__ W1,
                            const float* __restrict__ W2,
                            const int* __restrict__ ecol,
                            ushort* __restrict__ w1abt,
                            ushort* __restrict__ w2t,
                            int* __restrict__ hist,
                            int* __restrict__ rank,
                            int E, int n_nodes)
{
    int gid = blockIdx.x * blockDim.x + threadIdx.x;
    if (gid < NCH * D) {
        int oc = gid >> 7, k = gid & 127;
        float v;
        if (oc < 128) v = W1[k * D + oc] - W1[(k + 128) * D + oc];
        else          v = W1[(k + 128) * D + (oc - 128)];
        w1abt[gid] = f2h(v);
    } else if (gid < NCH * D + D * D) {
        int id2 = gid - NCH * D;
        int oc = id2 >> 7, k = id2 & 127;
        w2t[id2] = f2h(W2[k * D + oc]);
    } else {
        int e = gid - (NCH * D + D * D);
        if (e < E) {
            int c = ecol[e];
            if ((unsigned)c >= (unsigned)n_nodes) c = 0;
            rank[e] = atomicAdd(&hist[c], 1);
        }
    }
}

// ---------- scan stage 1: per-block sums ----------
__global__ void scan1_kernel(const int* __restrict__ hist, int* __restrict__ partial, int N)
{
    __shared__ int s[256];
    int tid = threadIdx.x;
    int i = blockIdx.x * 256 + tid;
    s[tid] = (i < N) ? hist[i] : 0;
    __syncthreads();
    #pragma unroll
    for (int off = 128; off > 0; off >>= 1) {
        if (tid < off) s[tid] += s[tid + off];
        __syncthreads();
    }
    if (tid == 0) partial[blockIdx.x] = s[0];
}

// ---------- scan stage 2+3 fused ----------
__global__ void scan23_kernel(const int* __restrict__ hist, const int* __restrict__ partial,
                              int* __restrict__ ofs,
                              int nb, int N, int E)
{
    __shared__ int sp[256];
    __shared__ int s[256];
    int tid = threadIdx.x;

    int pv = (tid < nb) ? partial[tid] : 0;
    sp[tid] = pv;
    __syncthreads();
    #pragma unroll
    for (int off = 1; off < 256; off <<= 1) {
        int t = (tid >= off) ? sp[tid - off] : 0;
        __syncthreads();
        sp[tid] += t;
        __syncthreads();
    }
    const int bofs = (blockIdx.x > 0) ? sp[blockIdx.x - 1] : 0;

    int i = blockIdx.x * 256 + tid;
    int v = (i < N) ? hist[i] : 0;
    s[tid] = v;
    __syncthreads();
    #pragma unroll
    for (int off = 1; off < 256; off <<= 1) {
        int t = (tid >= off) ? s[tid - off] : 0;
        __syncthreads();
        s[tid] += t;
        __syncthreads();
    }
    if (i < N) ofs[i] = bofs + s[tid] - v;
    if (blockIdx.x == 0 && tid == 0) ofs[N] = E;
}

// ---------- fused: pab blocks [0,npab) + atomic-free scatter blocks [npab, ...) ----------
__global__ __launch_bounds__(256) void scatter_pab_kernel(
    const float* __restrict__ x,
    const ushort* __restrict__ w1abt,
    const float* __restrict__ b1,
    ushort* __restrict__ pab,
    const int* __restrict__ erow, const int* __restrict__ ecol,
    const int* __restrict__ nofs,
    const int* __restrict__ rank,
    unsigned* __restrict__ spk,
    int E, int n_nodes, int npab)
{
    __shared__ ushort A[64 * 128];   // used by pab blocks only
    const int tid = threadIdx.x;

    if ((int)blockIdx.x >= npab) {
        // ===== scatter: pure loads + one random store per edge, no atomics =====
        const int stride = (gridDim.x - npab) * 256;
        const int e0 = ((int)blockIdx.x - npab) * 256 + tid;
        int cc[SC_ILP], rr[SC_ILP], rk[SC_ILP];
        #pragma unroll
        for (int j = 0; j < SC_ILP; ++j) {
            int e = e0 + j * stride;
            if (e < E) {
                int c = ecol[e];
                if ((unsigned)c >= (unsigned)n_nodes) c = 0;
                int r = erow[e];
                if ((unsigned)r >= (unsigned)n_nodes) r = 0;
                cc[j] = c; rr[j] = r; rk[j] = rank[e];
            } else cc[j] = -1;
        }
        int pos[SC_ILP];
        #pragma unroll
        for (int j = 0; j < SC_ILP; ++j)
            if (cc[j] >= 0) pos[j] = nofs[cc[j]] + rk[j];
        #pragma unroll
        for (int j = 0; j < SC_ILP; ++j)
            if (cc[j] >= 0) spk[pos[j]] = (unsigned)cc[j] | ((unsigned)rr[j] << 16);
        return;
    }

    // ===== pab: Pab = x(fp16) @ [W1a | W1b] (+b1 folded into Pa') =====
    const int base = blockIdx.x * 64;

    #pragma unroll
    for (int it = 0; it < 8; ++it) {
        int idx4 = it * 256 + tid;       // float4 index in 64x128 tile
        int row = idx4 >> 5;
        int c4  = idx4 & 31;
        int node = base + row;
        float4 vx = make_float4(0.f, 0.f, 0.f, 0.f);
        if (node < n_nodes) vx = ((const float4*)x)[(size_t)node * 32 + c4];
        f16x4 o;
        o[0] = (_Float16)vx.x; o[1] = (_Float16)vx.y;
        o[2] = (_Float16)vx.z; o[3] = (_Float16)vx.w;
        *(f16x4*)((char*)A + row * 256 + ((c4 * 8) ^ ((row & 7) << 4))) = o;
    }
    __syncthreads();

    const int l = tid & 63, w = tid >> 6;
    const int l15 = l & 15, lq = l >> 4;

    f32x4 acc[4][4];                 // [channel frag][node frag]
    #pragma unroll
    for (int cf = 0; cf < 4; ++cf)
        #pragma unroll
        for (int rf = 0; rf < 4; ++rf)
            acc[cf][rf] = (f32x4){0.f, 0.f, 0.f, 0.f};

    #pragma unroll
    for (int kk = 0; kk < 4; ++kk) {
        f16x8 a[4], b[4];
        #pragma unroll
        for (int cf = 0; cf < 4; ++cf)
            a[cf] = *(const f16x8*)(w1abt + (w * 64 + cf * 16 + l15) * 128 + kk * 32 + lq * 8);
        #pragma unroll
        for (int rf = 0; rf < 4; ++rf) {
            int row = rf * 16 + l15;
            b[rf] = *(const f16x8*)((const char*)A + row * 256 + ((kk * 64 + lq * 16) ^ ((row & 7) << 4)));
        }
        #pragma unroll
        for (int cf = 0; cf < 4; ++cf)
            #pragma unroll
            for (int rf = 0; rf < 4; ++rf)
                acc[cf][rf] = __builtin_amdgcn_mfma_f32_16x16x32_f16(a[cf], b[rf], acc[cf][rf], 0, 0, 0);
    }

    // D[ch][node]: node = rf*16 + l15 (lane), ch = w*64 + cf*16 + lq*4 + r
    #pragma unroll
    for (int rf = 0; rf < 4; ++rf) {
        int node = base + rf * 16 + l15;
        if (node < n_nodes) {
            #pragma unroll
            for (int cf = 0; cf < 4; ++cf) {
                int ch = w * 64 + cf * 16 + lq * 4;
                float4 bb = (w < 2) ? *(const float4*)(b1 + ch) : make_float4(0.f, 0.f, 0.f, 0.f);
                f16x4 o;
                o[0] = (_Float16)(acc[cf][rf][0] + bb.x);
                o[1] = (_Float16)(acc[cf][rf][1] + bb.y);
                o[2] = (_Float16)(acc[cf][rf][2] + bb.z);
                o[3] = (_Float16)(acc[cf][rf][3] + bb.w);
                *(f16x4*)(pab + (size_t)node * NCH + ch) = o;
            }
        }
    }
}

// ================= main: bucket Pa' cached in LDS; row-side-only global gather (R19-exact) =================
__global__ __launch_bounds__(256, 4) void edgeconv_main(
    const ushort* __restrict__ pab,
    const ushort* __restrict__ w2t,
    const unsigned* __restrict__ spk,
    const int* __restrict__ nofs,     // node-level offsets [n_nodes+1]
    const float* __restrict__ b2,
    float* __restrict__ out,
    int E, int n_nodes)
{
    __shared__ unsigned outbuf[BNODES * D];      // 8KB encoded running max
    __shared__ ushort Hs[TILE * D];              // 16KB h tile (fp16, swizzled)
    __shared__ ushort PaL[BNODES * PSTRIDE];     // 4.25KB bucket Pa' cache (row stride 272B)
    __shared__ int colidx[TILE];
    __shared__ int rowidx[TILE];

    const int tid = threadIdx.x;

    // XCD-bijective bucket swizzle
    const int nwg = gridDim.x, orig = blockIdx.x;
    const int q = nwg >> 3, rr = nwg & 7, xcd = orig & 7;
    const int bucket = (xcd < rr ? xcd * (q + 1) : rr * (q + 1) + (xcd - rr) * q) + (orig >> 3);

    const int base = bucket * BNODES;
    const int nend = min(base + BNODES, n_nodes);
    const int estart = nofs[base];
    const int eend = nofs[nend];

    #pragma unroll
    for (int i = 0; i < 8; ++i) outbuf[tid + i * 256] = 0u;

    const int l = tid & 63, w = tid >> 6;
    const int l15 = l & 15, lq = l >> 4;
    const int cg = tid & 15, esub = tid >> 4;
    const f16x8 zero = {0, 0, 0, 0, 0, 0, 0, 0};
    const unsigned padp = (unsigned)base | ((unsigned)base << 16);

    // load bucket's Pa' (16 nodes x 128 ch) into LDS once: each thread one 16B chunk
    {
        int node = tid >> 4;             // 0..15
        int ch = (tid & 15) * 8;         // 0..120
        int gn = base + node;
        f16x8 v = zero;
        if (gn < n_nodes) v = *(const f16x8*)(pab + (size_t)gn * NCH + ch);
        *(f16x8*)(PaL + node * PSTRIDE + ch) = v;
    }

    // prologue: prefetch tile-0 packed indices (1 VGPR held across phases)
    unsigned px = padp;
    if (tid < TILE && estart + tid < eend) px = spk[estart + tid];

    for (int t0 = estart; t0 < eend; t0 += TILE) {
        const int n = min(TILE, eend - t0);
        __syncthreads();   // prior tile's MFMA/epilogue done; also covers PaL visibility at t=0
        if (tid < TILE) {
            colidx[tid] = (int)(px & 0xffffu);
            rowidx[tid] = (int)(px >> 16);
            int nt = t0 + TILE + tid;
            px = (nt < eend) ? spk[nt] : padp;
        }
        __syncthreads();

        // ---- gather + layer 1: h = relu(PaL[col-base] + Pb[row]) -> Hs
        {
            f16x8 vb[4];
            #pragma unroll
            for (int it = 0; it < 4; ++it) {
                int e = it * 16 + esub;
                int r = rowidx[e];
                vb[it] = *(const f16x8*)(pab + (size_t)r * NCH + 128 + cg * 8);
            }
            #pragma unroll
            for (int it = 0; it < 4; ++it) {
                int e = it * 16 + esub;
                int c = colidx[e] - base;
                f16x8 va = *(const f16x8*)(PaL + c * PSTRIDE + cg * 8);
                f16x8 h = __builtin_elementwise_max(va + vb[it], zero);
                *(f16x8*)((char*)Hs + e * 256 + ((cg * 16) ^ ((e & 7) << 4))) = h;
            }
        }
        __syncthreads();

        // ---- layer 2: [64 x 128] @ [128 x 128]; wave w owns cols [w*32, w*32+32)
        f32x4 acc[4][2];
        #pragma unroll
        for (int mf = 0; mf < 4; ++mf)
            #pragma unroll
            for (int nf = 0; nf < 2; ++nf)
                acc[mf][nf] = (f32x4){0.f, 0.f, 0.f, 0.f};

        #pragma unroll
        for (int kk = 0; kk < 4; ++kk) {
            f16x8 a[4], b[2];
            #pragma unroll
            for (int mf = 0; mf < 4; ++mf) {
                int row = mf * 16 + l15;
                a[mf] = *(const f16x8*)((const char*)Hs + row * 256 + ((kk * 64 + lq * 16) ^ ((row & 7) << 4)));
            }
            #pragma unroll
            for (int nf = 0; nf < 2; ++nf) {
                int col = w * 32 + nf * 16 + l15;
                b[nf] = *(const f16x8*)(w2t + col * 128 + kk * 32 + lq * 8);
            }
            #pragma unroll
            for (int mf = 0; mf < 4; ++mf)
                #pragma unroll
                for (int nf = 0; nf < 2; ++nf)
                    acc[mf][nf] = __builtin_amdgcn_mfma_f32_16x16x32_f16(a[mf], b[nf], acc[mf][nf], 0, 0, 0);
        }

        // ---- epilogue: encoded LDS atomicMax (plain layout)
        #pragma unroll
        for (int nf = 0; nf < 2; ++nf) {
            int col = w * 32 + nf * 16 + l15;
            #pragma unroll
            for (int mf = 0; mf < 4; ++mf) {
                #pragma unroll
                for (int r = 0; r < 4; ++r) {
                    int row = mf * 16 + lq * 4 + r;
                    if (row < n) {
                        int node = colidx[row] - base;
                        unsigned bs = __float_as_uint(acc[mf][nf][r]);
                        unsigned enc = (bs & 0x80000000u) ? ~bs : (bs | 0x80000000u);
                        atomicMax(&outbuf[node * D + col], enc);
                    }
                }
            }
        }
    }
    __syncthreads();

    // ---- write 16 nodes x 128 ch, decode + b2, empty -> 0, coalesced float4
    const int n0 = tid >> 4;            // 0..15
    const int c0 = (tid & 15) * 8;      // 8 channels per thread
    const int gnode = base + n0;
    if (gnode < n_nodes) {
        #pragma unroll
        for (int j = 0; j < 2; ++j) {
            float4 o;
            #pragma unroll
            for (int k = 0; k < 4; ++k) {
                int ch = c0 + j * 4 + k;
                unsigned u = outbuf[n0 * D + ch];
                float v;
                if (u == 0u) v = 0.f;
                else {
                    unsigned bs = (u & 0x80000000u) ? (u & 0x7fffffffu) : ~u;
                    v = __uint_as_float(bs) + b2[ch];
                }
                ((float*)&o)[k] = v;
            }
            *(float4*)(out + (size_t)gnode * D + c0 + j * 4) = o;
        }
    }
}

extern "C" void kernel_launch(void* const* d_in, const int* in_sizes, int n_in,
                              void* d_out, int out_size, void* d_ws, size_t ws_size,
                              hipStream_t stream)
{
    const float* x  = (const float*)d_in[0];
    const int* eidx = (const int*)d_in[1];
    const float* W1 = (const float*)d_in[2];
    const float* b1 = (const float*)d_in[3];
    const float* W2 = (const float*)d_in[4];
    const float* b2 = (const float*)d_in[5];

    const int n_nodes = in_sizes[0] / D;      // 50000 (< 65536 -> packed pairs valid)
    const int E = in_sizes[1] / 2;
    const int* erow = eidx;        // edge_index[0]
    const int* ecol = eidx + E;    // edge_index[1]

    const int nb_scan = (n_nodes + 255) / 256;                  // 196 <= 256
    const int nbuckets = (n_nodes + BNODES - 1) / BNODES;       // 3125
    const int npab = (n_nodes + 63) / 64;                       // 782
    const int nsc = (E + 256 * SC_ILP - 1) / (256 * SC_ILP);    // 586

    // ---- workspace layout
    char* ws = (char*)d_ws;
    size_t off = 0;
    ushort* pab = (ushort*)(ws + off);   off += (size_t)n_nodes * NCH * sizeof(ushort);
    off = (off + 255) & ~(size_t)255;
    ushort* w1abt = (ushort*)(ws + off); off += (size_t)NCH * D * sizeof(ushort);
    ushort* w2t = (ushort*)(ws + off);   off += (size_t)D * D * sizeof(ushort);
    off = (off + 255) & ~(size_t)255;
    int* hist = (int*)(ws + off);        off += (size_t)n_nodes * 4;
    off = (off + 255) & ~(size_t)255;
    int* nofs = (int*)(ws + off);        off += (size_t)(n_nodes + 1) * 4;
    off = (off + 255) & ~(size_t)255;
    int* rank = (int*)(ws + off);        off += (size_t)E * 4;
    off = (off + 255) & ~(size_t)255;
    int* partial = (int*)(ws + off);     off += 256 * 4;
    off = (off + 255) & ~(size_t)255;
    unsigned* spk = (unsigned*)(ws + off); off += (size_t)E * 4;

    float* out = (float*)d_out;

    hipMemsetAsync(hist, 0, (size_t)n_nodes * sizeof(int), stream);

    const int prep_work = NCH * D + D * D + E;
    prep_kernel<<<(prep_work + 255) / 256, 256, 0, stream>>>(W1, W2, ecol, w1abt, w2t, hist, rank, E, n_nodes);

    scan1_kernel<<<nb_scan, 256, 0, stream>>>(hist, partial, n_nodes);
    scan23_kernel<<<nb_scan, 256, 0, stream>>>(hist, partial, nofs, nb_scan, n_nodes, E);

    scatter_pab_kernel<<<npab + nsc, 256, 0, stream>>>(x, w1abt, b1, pab, erow, ecol,
                                                       nofs, rank, spk, E, n_nodes, npab);

    edgeconv_main<<<nbuckets, 256, 0, stream>>>(pab, w2t, spk, nofs, b2, out, E, n_nodes);
}